// Round 7
// baseline (285.452 us; speedup 1.0000x reference)
//
#include <hip/hip_runtime.h>

// Problem constants
#define B_ 8
#define N_ 2048
#define T_ 12
#define F_ 64
#define NT 24576    // N_*T_
#define CH 192      // 3 * 64 output channels
#define C_ 768      // 64 * 12 rows per diffusion GEMM B-operand

typedef __bf16 bf16x8 __attribute__((ext_vector_type(8)));
typedef float f32x4 __attribute__((ext_vector_type(4)));

typedef const __attribute__((address_space(1))) unsigned int as1_uint;
typedef __attribute__((address_space(3))) unsigned int as3_uint;

__device__ __forceinline__ void gload16(const void* g, void* l) {
  __builtin_amdgcn_global_load_lds((as1_uint*)g, (as3_uint*)l, 16, 0, 0);
}

__device__ __forceinline__ unsigned short f2bf(float f) {
  unsigned int u = __float_as_uint(f);
  u += 0x7FFFu + ((u >> 16) & 1u);   // RNE
  return (unsigned short)(u >> 16);
}

__device__ __forceinline__ float leaky(float v) {
  return v >= 0.0f ? v : 0.01f * v;
}

// ---------------------------------------------------------------------------
// adj fp32 -> bf16
// ---------------------------------------------------------------------------
__global__ __launch_bounds__(256) void convert_adj_k(const float* __restrict__ adj,
                                                     unsigned short* __restrict__ adjb) {
  size_t i = (size_t)blockIdx.x * 256 + threadIdx.x;
  const float4 v = reinterpret_cast<const float4*>(adj)[i];
  ushort4 u;
  u.x = f2bf(v.x); u.y = f2bf(v.y); u.z = f2bf(v.z); u.w = f2bf(v.w);
  reinterpret_cast<ushort4*>(adjb)[i] = u;
}

// ---------------------------------------------------------------------------
// Stage W^T (bf16, padded rows of 72) + bias into LDS. W is [64 f][64 o].
// ---------------------------------------------------------------------------
__device__ __forceinline__ void stage_wt(const float* __restrict__ W,
                                         unsigned short* Wt, int tid) {
  const int f = tid >> 2;
  const int q = tid & 3;
  const float4* row = reinterpret_cast<const float4*>(W + f * 64 + q * 16);
#pragma unroll
  for (int v4 = 0; v4 < 4; ++v4) {
    float4 v = row[v4];
    const int ob = q * 16 + v4 * 4;
    Wt[(ob + 0) * 72 + f] = f2bf(v.x);
    Wt[(ob + 1) * 72 + f] = f2bf(v.y);
    Wt[(ob + 2) * 72 + f] = f2bf(v.z);
    Wt[(ob + 3) * 72 + f] = f2bf(v.w);
  }
}

// ---------------------------------------------------------------------------
// p0_k: out[:, 0:64] = leaky(x . W0 + b0)   via MFMA, linear-e mapping.
// ---------------------------------------------------------------------------
__global__ __launch_bounds__(256) void p0_k(const float* __restrict__ x,
                                            const float* __restrict__ W0,
                                            const float* __restrict__ bia0,
                                            float* __restrict__ out) {
  __shared__ unsigned short Wt[64 * 72];
  __shared__ float bias[64];
  const int tid = threadIdx.x;
  stage_wt(W0, Wt, tid);
  if (tid < 64) bias[tid] = bia0[tid];
  __syncthreads();

  const int lane = tid & 63;
  const int wave = tid >> 6;
  const int b = blockIdx.y;
  const int e = blockIdx.x * 64 + wave * 16 + (lane & 15);
  const int fgrp = (lane >> 4) * 8;
  const float* xb = x + (size_t)b * F_ * NT;

  bf16x8 xf[2];
#pragma unroll
  for (int kf = 0; kf < 2; ++kf)
#pragma unroll
    for (int j = 0; j < 8; ++j)
      xf[kf][j] = (__bf16)xb[(size_t)(fgrp + kf * 32 + j) * NT + e];

  float* outb = out + (size_t)b * CH * NT;
#pragma unroll
  for (int ob = 0; ob < 4; ++ob) {
    f32x4 acc = {};
#pragma unroll
    for (int kf = 0; kf < 2; ++kf) {
      bf16x8 af = *reinterpret_cast<const bf16x8*>(
          &Wt[(ob * 16 + (lane & 15)) * 72 + kf * 32 + fgrp]);
      acc = __builtin_amdgcn_mfma_f32_16x16x32_bf16(af, xf[kf], acc, 0, 0, 0);
    }
#pragma unroll
    for (int r = 0; r < 4; ++r) {
      const int o = ob * 16 + (lane >> 4) * 4 + r;
      outb[(size_t)o * NT + e] = leaky(acc[r] + bias[o]);
    }
  }
}

// ---------------------------------------------------------------------------
// p12_k: G1 = x.W1 + b1, G2 = x.W2 + b2 (no activation), bf16 to
// G_p[(o*12+t)*N_ + n]  (K-contig for GEMM).
// ---------------------------------------------------------------------------
__global__ __launch_bounds__(256) void p12_k(const float* __restrict__ x,
                                             const float* __restrict__ W1,
                                             const float* __restrict__ bia1,
                                             const float* __restrict__ W2,
                                             const float* __restrict__ bia2,
                                             unsigned short* __restrict__ G1,
                                             unsigned short* __restrict__ G2) {
  __shared__ unsigned short Wt[2][64 * 72];
  __shared__ float bias[2][64];
  const int tid = threadIdx.x;
  stage_wt(W1, Wt[0], tid);
  stage_wt(W2, Wt[1], tid);
  if (tid < 64) bias[0][tid] = bia1[tid];
  else if (tid < 128) bias[1][tid - 64] = bia2[tid - 64];
  __syncthreads();

  const int lane = tid & 63;
  const int wave = tid >> 6;
  const int b = blockIdx.y;
  const int n = blockIdx.x * 16 + (lane & 15);
  const int fgrp = (lane >> 4) * 8;
  const float* xb = x + (size_t)b * F_ * NT;
  unsigned short* Gp[2] = {G1 + (size_t)b * C_ * N_, G2 + (size_t)b * C_ * N_};

#pragma unroll
  for (int it = 0; it < 3; ++it) {
    const int t = wave * 3 + it;
    const int e = n * T_ + t;

    bf16x8 xf[2];
#pragma unroll
    for (int kf = 0; kf < 2; ++kf)
#pragma unroll
      for (int j = 0; j < 8; ++j)
        xf[kf][j] = (__bf16)xb[(size_t)(fgrp + kf * 32 + j) * NT + e];

#pragma unroll
    for (int p = 0; p < 2; ++p) {
#pragma unroll
      for (int ob = 0; ob < 4; ++ob) {
        f32x4 acc = {};
#pragma unroll
        for (int kf = 0; kf < 2; ++kf) {
          bf16x8 af = *reinterpret_cast<const bf16x8*>(
              &Wt[p][(ob * 16 + (lane & 15)) * 72 + kf * 32 + fgrp]);
          acc = __builtin_amdgcn_mfma_f32_16x16x32_bf16(af, xf[kf], acc, 0, 0, 0);
        }
#pragma unroll
        for (int r = 0; r < 4; ++r) {
          const int o = ob * 16 + (lane >> 4) * 4 + r;
          Gp[p][(size_t)(o * T_ + t) * N_ + n] = f2bf(acc[r] + bias[p][o]);
        }
      }
    }
  }
}

// ---------------------------------------------------------------------------
// 128x192 diffusion GEMM, STATIC 60KB LDS, 3-slot plane pipeline, 2 blocks/CU.
// C[n][c] = sum_m adj[b][n][m] * Bt[b][c][m],  K = 2048, plane BK = 32.
// 256 threads = 4 waves (1M x 4N), per-wave output 128x48, acc[8][3].
//
// Static LDS (compiler-visible => it keeps the fragment-pipeline registers
// instead of rematerializing ds_reads; rounds 4-6 VGPR=108 showed dynamic-LDS
// builds collapsed the pipeline). 3 slots x 20KB = 60KB; 2 blocks co-resident
// per CU (122KB of 160KB) decouple staging/compute across blocks.
//
// Plane p (cols [32p,32p+32)): slot p%3. Phase p:
//   STG plane p+2 -> slot (p+2)%3 (5 gloads/wave) ; vmcnt(5) [plane p+1
//   landed, per wave] ; s_barrier ; ds_read plane p+1 -> regset (p+1)&1 ;
//   sched_barrier ; setprio(1) ; MFMA24 regset p&1 ; sched_barrier ;
//   setprio(0) ; s_barrier.
// Slot overwrite (p+2 over p-1) is 1 barrier after plane p-1's reads done.
//
// Conflict-free LDS via granule XOR: LDS(r,g) holds global(r, g^((r>>1)&3));
// staging pre-swizzles the per-lane GLOBAL source granule (linear gload_lds
// dest); reads bake the XOR into lane constant kg. B rows exactly 192 (no
// padding waste).
// grid 512 = 8 batches x (16 n-tiles x 4 c-tiles); blockIdx&7 = batch = XCD.
// ---------------------------------------------------------------------------
#define SLOTSZ 10240   // shorts: A [128][32] = 4096, B [192][32] = 6144

__global__ __launch_bounds__(256, 2) void gemm8_k(
    const unsigned short* __restrict__ adjb,
    const unsigned short* __restrict__ Bt,
    float* __restrict__ out,
    unsigned short* __restrict__ Ht,
    const int mode, const int ochan_base)
{
  __shared__ __align__(16) unsigned short lds[3][SLOTSZ];  // 61440 B static

  const int tid  = threadIdx.x;
  const int lane = tid & 63;
  const int wave = tid >> 6;     // 0..3
  const int wc = wave;           // N quarter (48 cols each)

  const int b  = blockIdx.x & 7;            // batch == XCD (round-robin)
  const int j  = blockIdx.x >> 3;           // 0..63
  const int n0 = (j & 15) * 128;
  const int c0 = (j >> 4) * 192;

  const unsigned short* A  = adjb + (size_t)b * N_ * N_;
  const unsigned short* Bm = Bt   + (size_t)b * C_ * N_;

  // staging source pointers: lane covers row (lane>>2) within a 16-row band,
  // source col granule pre-swizzled.
  const int swzSrc = ((lane & 3) ^ ((lane >> 3) & 3)) * 8;   // shorts
  const unsigned short* aS0 = A + (size_t)(n0 + wave * 32 +  0 + (lane >> 2)) * N_ + swzSrc;
  const unsigned short* aS1 = A + (size_t)(n0 + wave * 32 + 16 + (lane >> 2)) * N_ + swzSrc;
  const unsigned short* bS0 = Bm + (size_t)(c0 + wave * 48 +  0 + (lane >> 2)) * N_ + swzSrc;
  const unsigned short* bS1 = Bm + (size_t)(c0 + wave * 48 + 16 + (lane >> 2)) * N_ + swzSrc;
  const unsigned short* bS2 = Bm + (size_t)(c0 + wave * 48 + 32 + (lane >> 2)) * N_ + swzSrc;

  // fragment read lane offset (shorts), swizzled k-granule
  const int kg  = (lane >> 4) ^ ((lane >> 1) & 3);
  const int rdL = (lane & 15) * 32 + kg * 8;
  const int bOff = 4096 + wc * 1536;

  f32x4 acc[8][3] = {};
  bf16x8 afr0[8], afr1[8], bfr0[3], bfr1[3];

#define STG(S, KT) \
  gload16(aS0 + (KT) * 32, &lds[S][wave * 1024]); \
  gload16(aS1 + (KT) * 32, &lds[S][wave * 1024 + 512]); \
  gload16(bS0 + (KT) * 32, &lds[S][4096 + wave * 1536]); \
  gload16(bS1 + (KT) * 32, &lds[S][4096 + wave * 1536 + 512]); \
  gload16(bS2 + (KT) * 32, &lds[S][4096 + wave * 1536 + 1024]);

#define RD(SET, S) { \
  _Pragma("unroll") \
  for (int nf = 0; nf < 3; ++nf) \
    bfr##SET[nf] = *(const bf16x8*)(&lds[S][bOff + nf * 512 + rdL]); \
  _Pragma("unroll") \
  for (int mm = 0; mm < 8; ++mm) \
    afr##SET[mm] = *(const bf16x8*)(&lds[S][mm * 512 + rdL]); }

#define MFMA24(SET) { \
  _Pragma("unroll") \
  for (int mm = 0; mm < 8; ++mm) \
  _Pragma("unroll") \
  for (int nf = 0; nf < 3; ++nf) \
    acc[mm][nf] = __builtin_amdgcn_mfma_f32_16x16x32_bf16( \
        afr##SET[mm], bfr##SET[nf], acc[mm][nf], 0, 0, 0); }

#define WAITV_(N) asm volatile("s_waitcnt vmcnt(" #N ")" ::: "memory");
#define WAITV(N) WAITV_(N)

#define PHASE(SETC, SETN, SN, SS, KT) \
  STG(SS, KT) \
  WAITV(5) \
  __builtin_amdgcn_s_barrier(); \
  RD(SETN, SN) \
  __builtin_amdgcn_sched_barrier(0); \
  __builtin_amdgcn_s_setprio(1); \
  MFMA24(SETC) \
  __builtin_amdgcn_sched_barrier(0); \
  __builtin_amdgcn_s_setprio(0); \
  __builtin_amdgcn_s_barrier();

  // ---- prologue: stage planes 0,1 (10 loads); read plane 0 -> set0
  STG(0, 0)
  STG(1, 1)
  WAITV(5)                                   // plane 0 landed
  __builtin_amdgcn_s_barrier();
  RD(0, 0)

  // ---- main loop: it = 0..9, phases p = 6it..6it+5 (stage planes 2..61)
#pragma unroll 1
  for (int it = 0; it < 10; ++it) {
    const int kt = 6 * it;
    PHASE(0, 1, 1, 2, kt + 2)   // p=6it+0: mfma slot0, read slot1, stage slot2
    PHASE(1, 0, 2, 0, kt + 3)   // p=6it+1
    PHASE(0, 1, 0, 1, kt + 4)   // p=6it+2
    PHASE(1, 0, 1, 2, kt + 5)   // p=6it+3
    PHASE(0, 1, 2, 0, kt + 6)   // p=6it+4
    PHASE(1, 0, 0, 1, kt + 7)   // p=6it+5
  }

  // ---- tail: phases 60..63 (stage planes 62, 63)
  PHASE(0, 1, 1, 2, 62)         // p=60: mfma slot0, read slot1, stage slot2
  PHASE(1, 0, 2, 0, 63)         // p=61: mfma slot1, read slot2, stage slot0
  // p=62: mfma slot2 (set0), read slot0 (plane 63), drain all
  WAITV(0)
  __builtin_amdgcn_s_barrier();
  RD(1, 0)
  __builtin_amdgcn_sched_barrier(0);
  __builtin_amdgcn_s_setprio(1);
  MFMA24(0)
  __builtin_amdgcn_sched_barrier(0);
  __builtin_amdgcn_s_setprio(0);
  __builtin_amdgcn_s_barrier();
  // p=63: mfma plane 63 (set1)
  __builtin_amdgcn_s_setprio(1);
  MFMA24(1)
  __builtin_amdgcn_s_setprio(0);

  // ---- epilogue. D frag: col(c) = lane&15, row(n) = (lane>>4)*4 + reg
  const int r4 = (lane >> 4) * 4;
  if (mode == 0) {
    float* outb = out + (size_t)b * CH * NT;
#pragma unroll
    for (int m = 0; m < 8; ++m) {
#pragma unroll
      for (int nf = 0; nf < 3; ++nf) {
        const int c = c0 + wc * 48 + nf * 16 + (lane & 15);
        const int o = c / 12;
        const int t = c - o * 12;
#pragma unroll
        for (int r = 0; r < 4; ++r) {
          const int n = n0 + m * 16 + r4 + r;
          outb[((size_t)(ochan_base + o) * N_ + n) * T_ + t] = leaky(acc[m][nf][r]);
        }
      }
    }
  } else {
    unsigned short* Hb = Ht + (size_t)b * C_ * N_;
#pragma unroll
    for (int m = 0; m < 8; ++m) {
#pragma unroll
      for (int nf = 0; nf < 3; ++nf) {
        const int c = c0 + wc * 48 + nf * 16 + (lane & 15);
        const int nb = n0 + m * 16 + r4;
        ushort4 u;
        u.x = f2bf(acc[m][nf][0]);
        u.y = f2bf(acc[m][nf][1]);
        u.z = f2bf(acc[m][nf][2]);
        u.w = f2bf(acc[m][nf][3]);
        *reinterpret_cast<ushort4*>(&Hb[(size_t)c * N_ + nb]) = u;
      }
    }
  }
#undef STG
#undef RD
#undef MFMA24
#undef PHASE
#undef WAITV
#undef WAITV_
}

// ---------------------------------------------------------------------------
// Workspace layout (bytes):
//   adjb : [0, 67108864)                 8*2048*2048 bf16
//   G1   : [67108864, 92274688)          8*768*2048 bf16   (reused as Ht)
//   G2   : [92274688, 117440512)         8*768*2048 bf16
// ---------------------------------------------------------------------------
extern "C" void kernel_launch(void* const* d_in, const int* in_sizes, int n_in,
                              void* d_out, int out_size, void* d_ws, size_t ws_size,
                              hipStream_t stream) {
  const float* x   = (const float*)d_in[0];
  const float* adj = (const float*)d_in[1];
  const float* W0  = (const float*)d_in[2];
  const float* b0  = (const float*)d_in[3];
  const float* W1  = (const float*)d_in[4];
  const float* b1  = (const float*)d_in[5];
  const float* W2  = (const float*)d_in[6];
  const float* b2  = (const float*)d_in[7];
  float* out = (float*)d_out;

  char* ws = (char*)d_ws;
  unsigned short* adjb = (unsigned short*)ws;
  unsigned short* G1   = (unsigned short*)(ws + 67108864);
  unsigned short* G2   = (unsigned short*)(ws + 92274688);
  unsigned short* Ht   = G1;  // G1 dead after diffusion pass 1 -> reuse

  // 1) adj -> bf16
  hipLaunchKernelGGL(convert_adj_k, dim3((B_ * N_ * N_ / 4) / 256), dim3(256), 0, stream,
                     adj, adjb);

  // 2) p=0: out channels [0,64) directly
  hipLaunchKernelGGL(p0_k, dim3(NT / 64, B_), dim3(256), 0, stream,
                     x, W0, b0, out);

  // 3) p=1,2 feature transforms -> G1, G2 (bf16, [c][m] layout)
  hipLaunchKernelGGL(p12_k, dim3(N_ / 16, B_), dim3(256), 0, stream,
                     x, W1, b1, W2, b2, G1, G2);

  // 4) diffusion p=1: out[64:128] = leaky(adj @ G1)
  hipLaunchKernelGGL(gemm8_k, dim3(512), dim3(256), 0, stream,
                     adjb, G1, out, (unsigned short*)nullptr, 0, 64);

  // 5) diffusion p=2 hop 1: Ht = bf16(adj @ G2)
  hipLaunchKernelGGL(gemm8_k, dim3(512), dim3(256), 0, stream,
                     adjb, G2, out, Ht, 1, 0);

  // 6) diffusion p=2 hop 2: out[128:192] = leaky(adj @ Ht)
  hipLaunchKernelGGL(gemm8_k, dim3(512), dim3(256), 0, stream,
                     adjb, Ht, out, (unsigned short*)nullptr, 0, 128);
}